// Round 4
// baseline (291.087 us; speedup 1.0000x reference)
//
#include <hip/hip_runtime.h>
#include <math.h>

// Problem constants (static per reference)
#define B_    256
#define N_    400
#define D_    256
#define EPG_  12800          // N*DEG edges per graph (block-diagonal, contiguous)
#define E_    3276800        // B*EPG
#define NT_   102400         // B*N
#define K_    200            // ceil(0.5*N)
#define NKC_  200            // N-K

// Output flat offsets (float32 elements, in return order).
// O_FDIS..O_FCOM regions are contiguous, so concatenated output row
// r in [0, B*N) lives at out + r*D  (r < B*K => dis, else com).
#define O_FDIS 0
#define O_FCOM 13107200      // + B*K*D
#define O_PERM 26214400      // + B*NKC*D
#define O_PCOM 26265600      // + B*K
#define O_SOFT 26316800      // + B*NKC
#define O_EDIS 26419200      // + NT
#define O_ECOM 29696000      // + E

#define NEG_INF (-3.402823466e38f)

// Native clang vector type: __builtin_nontemporal_store rejects HIP's
// float4 class but accepts ext_vector_type. Same 16-B layout/alignment.
typedef float nfv4 __attribute__((ext_vector_type(4)));

static __device__ __forceinline__ void nt_store4(float4* p, float4 v) {
    nfv4 x; x.x = v.x; x.y = v.y; x.z = v.z; x.w = v.w;
    __builtin_nontemporal_store(x, (nfv4*)p);
}

// ---------------------------------------------------------------------------
// One block (1024 thr = 16 waves) per graph. Full per-graph pipeline:
//  P2: waves 0-11 feat@W (4 rows in flight each) || waves 12-15 degree hists
//  P4: normed scatter-sum (edges L2-hot)
//  P5: score + tanh table
//  P6: rank-select top-k IN REGISTERS (shfl broadcast, no LDS latency loop)
//      || wave 15 softmax partial
//  P7: complement positions from ballot masks (O(1) per thread)
//  P8: edge masks (edges L2-hot, nt stores)
//  P9: gated feature gather (feat re-read is L3-hot, nt stores)
// 7 barriers. LDS ~6.5 KB.
// ---------------------------------------------------------------------------
__global__ __launch_bounds__(1024) void k_graph(const float* __restrict__ feat,
                                                const float* __restrict__ W,
                                                const int* __restrict__ src,
                                                const int* __restrict__ dst,
                                                const float* __restrict__ bp,
                                                float* __restrict__ score,
                                                float* __restrict__ pm,
                                                float* __restrict__ ps,
                                                float* __restrict__ out) {
    __shared__ float hl[N_], scl[N_];
    __shared__ int   ho[N_], hi[N_];
    __shared__ unsigned long long bmask[7];
    // Phase-aliased views (temporally disjoint uses):
    int*   orow_l = ho;   // node -> output row   (valid from P6/P7)
    int*   smask  = hi;   // node -> selected?    (valid from P6)
    float* tl     = hl;   // node -> tanh(score)  (valid from P5)

    const int g = blockIdx.x, tid = threadIdx.x;
    const int nbase = g * N_, ebase = g * EPG_;
    const int wave = tid >> 6, lane = tid & 63;

    if (tid < N_) { ho[tid] = 0; hi[tid] = 0; scl[tid] = 0.0f; }
    __syncthreads();

    const int4* s4 = (const int4*)(src + ebase);   // 3200 int4
    const int4* d4 = (const int4*)(dst + ebase);
    const float4* fb = (const float4*)feat + (size_t)nbase * 64;

    if (wave < 12) {
        // --- feat @ W, 4 rows in flight per wave for MLP (48-row stride)
        const float4 w4 = ((const float4*)W)[lane];
        for (int r = wave; r < N_; r += 48) {
            const int r1 = r + 12, r2 = r + 24, r3 = r + 36;
            float4 a0 = fb[(size_t)r * 64 + lane];
            float4 a1 = (r1 < N_) ? fb[(size_t)r1 * 64 + lane] : make_float4(0.f,0.f,0.f,0.f);
            float4 a2 = (r2 < N_) ? fb[(size_t)r2 * 64 + lane] : make_float4(0.f,0.f,0.f,0.f);
            float4 a3 = (r3 < N_) ? fb[(size_t)r3 * 64 + lane] : make_float4(0.f,0.f,0.f,0.f);
            float d0 = a0.x*w4.x + a0.y*w4.y + a0.z*w4.z + a0.w*w4.w;
            float d1 = a1.x*w4.x + a1.y*w4.y + a1.z*w4.z + a1.w*w4.w;
            float d2 = a2.x*w4.x + a2.y*w4.y + a2.z*w4.z + a2.w*w4.w;
            float d3 = a3.x*w4.x + a3.y*w4.y + a3.z*w4.z + a3.w*w4.w;
            #pragma unroll
            for (int off = 32; off > 0; off >>= 1) {
                d0 += __shfl_down(d0, off, 64);
                d1 += __shfl_down(d1, off, 64);
                d2 += __shfl_down(d2, off, 64);
                d3 += __shfl_down(d3, off, 64);
            }
            if (lane == 0) {
                hl[r] = d0;
                if (r1 < N_) hl[r1] = d1;
                if (r2 < N_) hl[r2] = d2;
                if (r3 < N_) hl[r3] = d3;
            }
        }
    } else {
        // --- degree histograms: waves 12-15 (256 lanes)
        for (int i = tid - 768; i < EPG_ / 4; i += 256) {
            int4 s = s4[i]; int4 d = d4[i];
            atomicAdd(&ho[s.x - nbase], 1);
            atomicAdd(&ho[s.y - nbase], 1);
            atomicAdd(&ho[s.z - nbase], 1);
            atomicAdd(&ho[s.w - nbase], 1);
            atomicAdd(&hi[d.x - nbase], 1);
            atomicAdd(&hi[d.y - nbase], 1);
            atomicAdd(&hi[d.z - nbase], 1);
            atomicAdd(&hi[d.w - nbase], 1);
        }
    }
    __syncthreads();

    if (tid < N_)
        hl[tid] = hl[tid] * (1.0f / sqrtf(fmaxf((float)ho[tid], 1.0f)));
    __syncthreads();

    // --- P4: normed scatter-sum (edges now L2-hot), all 16 waves
    for (int i = tid; i < EPG_ / 4; i += 1024) {
        int4 s = s4[i]; int4 d = d4[i];
        atomicAdd(&scl[d.x - nbase], hl[s.x - nbase]);
        atomicAdd(&scl[d.y - nbase], hl[s.y - nbase]);
        atomicAdd(&scl[d.z - nbase], hl[s.z - nbase]);
        atomicAdd(&scl[d.w - nbase], hl[s.w - nbase]);
    }
    __syncthreads();

    // --- P5: score (+ tanh table; hl is dead, reuse as tl)
    const float bb = bp[0];
    if (tid < N_) {
        float v = scl[tid] * (1.0f / sqrtf(fmaxf((float)hi[tid], 1.0f))) + bb;
        scl[tid] = v;
        score[nbase + tid] = v;
        tl[tid] = tanhf(v);
    }
    __syncthreads();

    // --- P6: rank-select top-k in registers (waves 0-6; 448 lanes).
    // rank_i = #{j : s_j > s_i or (s_j == s_i and j < i)}; selected iff < K,
    // list position == rank (== lax.top_k stable-descending order).
    bool selb = false;
    if (tid < 448) {
        float sreg[7];
        #pragma unroll
        for (int t = 0; t < 7; ++t) {
            const int j = t * 64 + lane;
            sreg[t] = (j < N_) ? scl[j] : NEG_INF;
        }
        const float v = (tid < N_) ? scl[tid] : NEG_INF;
        int rnk = 0;
        #pragma unroll
        for (int t = 0; t < 7; ++t) {
            #pragma unroll
            for (int l2 = 0; l2 < 64; ++l2) {
                const float u = __shfl(sreg[t], l2, 64);
                const int j = t * 64 + l2;
                rnk += ((u > v) || (u == v && j < tid)) ? 1 : 0;
            }
        }
        selb = (tid < N_) && (rnk < K_);
        if (tid < N_) smask[tid] = selb ? 1 : 0;
        if (selb) {
            orow_l[tid] = g * K_ + rnk;                     // dis rows: [0, B*K)
            out[O_PERM + g * K_ + rnk] = (float)(nbase + tid);
        }
        unsigned long long bal = __ballot(selb);
        if (lane == 0) bmask[wave] = bal;
    }
    // Wave 15 computes the per-graph softmax partial from scl (read-only).
    if (wave == 15) {
        float m = NEG_INF;
        for (int i = lane; i < N_; i += 64) m = fmaxf(m, scl[i]);
        #pragma unroll
        for (int o = 32; o > 0; o >>= 1) m = fmaxf(m, __shfl_xor(m, o, 64));
        float s = 0.0f;
        for (int i = lane; i < N_; i += 64) s += expf(scl[i] - m);
        #pragma unroll
        for (int o = 32; o > 0; o >>= 1) s += __shfl_xor(s, o, 64);
        if (lane == 0) { pm[g] = m; ps[g] = s; }
    }
    __syncthreads();

    // --- P7: complement positions from ballot masks: pos = tid - #sel_below
    if (tid < N_ && !selb) {
        int nsel = 0;
        #pragma unroll
        for (int w = 0; w < 7; ++w)
            if (w < wave) nsel += (int)__popcll(bmask[w]);
        nsel += (int)__popcll(bmask[wave] & ((1ull << lane) - 1ull));
        const int pos = tid - nsel;
        orow_l[tid] = B_ * K_ + g * NKC_ + pos;             // com rows
        out[O_PCOM + g * NKC_ + pos] = (float)(nbase + tid);
    }
    __syncthreads();

    // --- P8: edge masks from LDS smask (edges still L2-hot); nt stores.
    float4* mdis = (float4*)(out + O_EDIS) + g * (EPG_ / 4);
    float4* mcom = (float4*)(out + O_ECOM) + g * (EPG_ / 4);
    for (int i = tid; i < EPG_ / 4; i += 1024) {
        int4 s = s4[i]; int4 d = d4[i];
        int a0 = smask[s.x - nbase], a1 = smask[s.y - nbase];
        int a2 = smask[s.z - nbase], a3 = smask[s.w - nbase];
        int b0 = smask[d.x - nbase], b1 = smask[d.y - nbase];
        int b2 = smask[d.z - nbase], b3 = smask[d.w - nbase];
        float4 vdis, vcom;
        vdis.x = (a0 & b0) ? 1.0f : 0.0f;  vcom.x = (a0 | b0) ? 0.0f : 1.0f;
        vdis.y = (a1 & b1) ? 1.0f : 0.0f;  vcom.y = (a1 | b1) ? 0.0f : 1.0f;
        vdis.z = (a2 & b2) ? 1.0f : 0.0f;  vcom.z = (a2 | b2) ? 0.0f : 1.0f;
        vdis.w = (a3 & b3) ? 1.0f : 0.0f;  vcom.w = (a3 | b3) ? 0.0f : 1.0f;
        nt_store4(&mdis[i], vdis);
        nt_store4(&mcom[i], vcom);
    }

    // --- P9: gated feature gather. feat re-read is L3-hot (read in P2).
    // Wave w handles nodes [w*25, w*25+25); 5 rows in flight for MLP.
    {
        const int base = wave * 25;
        for (int u = 0; u < 25; u += 5) {
            const int n0 = base + u, n1 = n0 + 1, n2 = n0 + 2, n3 = n0 + 3, n4 = n0 + 4;
            const int r0 = orow_l[n0], r1 = orow_l[n1], r2 = orow_l[n2],
                      r3 = orow_l[n3], r4 = orow_l[n4];
            const float t0 = tl[n0], t1 = tl[n1], t2 = tl[n2], t3 = tl[n3], t4 = tl[n4];
            float4 v0 = fb[(size_t)n0 * 64 + lane];
            float4 v1 = fb[(size_t)n1 * 64 + lane];
            float4 v2 = fb[(size_t)n2 * 64 + lane];
            float4 v3 = fb[(size_t)n3 * 64 + lane];
            float4 v4 = fb[(size_t)n4 * 64 + lane];
            v0.x *= t0; v0.y *= t0; v0.z *= t0; v0.w *= t0;
            v1.x *= t1; v1.y *= t1; v1.z *= t1; v1.w *= t1;
            v2.x *= t2; v2.y *= t2; v2.z *= t2; v2.w *= t2;
            v3.x *= t3; v3.y *= t3; v3.z *= t3; v3.w *= t3;
            v4.x *= t4; v4.y *= t4; v4.z *= t4; v4.w *= t4;
            nt_store4(((float4*)(out + (size_t)r0 * D_)) + lane, v0);
            nt_store4(((float4*)(out + (size_t)r1 * D_)) + lane, v1);
            nt_store4(((float4*)(out + (size_t)r2 * D_)) + lane, v2);
            nt_store4(((float4*)(out + (size_t)r3 * D_)) + lane, v3);
            nt_store4(((float4*)(out + (size_t)r4 * D_)) + lane, v4);
        }
    }
}

// ---------------------------------------------------------------------------
// Softmax outputs: 400 blocks x 256 thr; each block redundantly combines the
// 256 per-graph (max,sumexp) partials (1 KB each, L2/L3-hot) with a wave
// butterfly, then writes its 256-node slice. One node per thread.
// ---------------------------------------------------------------------------
__global__ __launch_bounds__(256) void k_soft(const float* __restrict__ score,
                                              const float* __restrict__ pm,
                                              const float* __restrict__ ps,
                                              float* __restrict__ out) {
    __shared__ float sm[4], ss[4];
    const int tid = threadIdx.x, lane = tid & 63, wv = tid >> 6;
    float m = pm[tid], s = ps[tid];
    #pragma unroll
    for (int o = 32; o > 0; o >>= 1) {
        float mo = __shfl_xor(m, o, 64);
        float so = __shfl_xor(s, o, 64);
        float M2 = fmaxf(m, mo);
        s = s * expf(m - M2) + so * expf(mo - M2);
        m = M2;
    }
    if (lane == 0) { sm[wv] = m; ss[wv] = s; }
    __syncthreads();
    const float M = fmaxf(fmaxf(sm[0], sm[1]), fmaxf(sm[2], sm[3]));
    const float S = ss[0] * expf(sm[0] - M) + ss[1] * expf(sm[1] - M)
                  + ss[2] * expf(sm[2] - M) + ss[3] * expf(sm[3] - M);
    const int n = blockIdx.x * 256 + tid;
    out[O_SOFT + n] = expf(score[n] - M) / S;
}

extern "C" void kernel_launch(void* const* d_in, const int* in_sizes, int n_in,
                              void* d_out, int out_size, void* d_ws, size_t ws_size,
                              hipStream_t stream) {
    const float* feat = (const float*)d_in[0];
    const float* W    = (const float*)d_in[1];
    const float* bp   = (const float*)d_in[2];
    const int*   src  = (const int*)d_in[3];
    const int*   dst  = (const int*)d_in[4];
    float* out = (float*)d_out;

    char* ws = (char*)d_ws;
    float* score = (float*)(ws + 0);         // NT_ floats
    float* pm    = (float*)(ws + 409600);    // B_ floats
    float* ps    = (float*)(ws + 410624);    // B_ floats

    k_graph<<<B_,       1024, 0, stream>>>(feat, W, src, dst, bp,
                                           score, pm, ps, out);   // 1 block / graph
    k_soft <<<NT_ / 256, 256, 0, stream>>>(score, pm, ps, out);   // 400 blocks
}